// Round 9
// baseline (7182.820 us; speedup 1.0000x reference)
//
#include <hip/hip_runtime.h>
#include <math.h>

#define B_N 32
#define T_N 1024
#define E_N 512
#define H_N 512
#define G4_N 2048  // 4*H

typedef __attribute__((ext_vector_type(8))) short short8;
typedef __attribute__((ext_vector_type(4))) float f32x4;
typedef unsigned long long ull;

__device__ __forceinline__ unsigned short f2bfu(float f) {
  unsigned int x = __builtin_bit_cast(unsigned int, f);
  x += 0x7fffu + ((x >> 16) & 1u);
  return (unsigned short)(x >> 16);
}
__device__ __forceinline__ float bfu2f(unsigned short u) {
  return __builtin_bit_cast(float, ((unsigned int)u) << 16);
}
__device__ __forceinline__ float sigmf(float x) { return 1.0f / (1.0f + expf(-x)); }

// fire-and-forget 8B message store (MALL-coherent, bypass L1/L2)
__device__ __forceinline__ void store_msg(ull* p, ull v) {
  asm volatile("global_store_dwordx2 %0, %1, off sc0 sc1" :: "v"(p), "v"(v) : "memory");
}

// ---------------------------------------------------------------------------
// Kernel 1 (unchanged): xw[dir][t_local][g][b] bf16 = W_ih[dir] @ x(+rev) + b
// ---------------------------------------------------------------------------
__global__ __launch_bounds__(256) void xw_gemm_kernel(
    const float* __restrict__ xs, const int* __restrict__ lengths,
    const float* __restrict__ w_ih_f, const float* __restrict__ b_f,
    const float* __restrict__ w_ih_b, const float* __restrict__ b_b,
    unsigned short* __restrict__ xw, int t0, int Tseg)
{
  __shared__ unsigned short As[64][80];
  __shared__ unsigned short Bs[64][80];
  const int g0 = blockIdx.x * 64;
  const int n0 = blockIdx.y * 64;
  const int dir = blockIdx.z;
  const float* __restrict__ W = dir ? w_ih_b : w_ih_f;
  const float* __restrict__ bias = dir ? b_b : b_f;
  const int tid = threadIdx.x;
  const int w = tid >> 6, lane = tid & 63;
  const int wr = w >> 1, wc = w & 1;

  const int sr = tid >> 2;
  const int sq = tid & 3;
  const int nrow = n0 + sr;
  const int bb = nrow & 31;
  const int tt = t0 + (nrow >> 5);
  const int Lb = lengths[bb];
  const int src_t = (dir != 0 && tt < Lb) ? (Lb - 1 - tt) : tt;
  const float* __restrict__ xrow = xs + ((size_t)bb * T_N + src_t) * E_N;
  const float* __restrict__ arow = W + (size_t)(g0 + sr) * E_N;

  f32x4 acc[2][2] = {};

  for (int k0 = 0; k0 < E_N; k0 += 64) {
    float4 av[4], bv[4];
#pragma unroll
    for (int i = 0; i < 4; ++i) {
      av[i] = *(const float4*)&arow[k0 + sq * 16 + i * 4];
      bv[i] = *(const float4*)&xrow[k0 + sq * 16 + i * 4];
    }
    __syncthreads();
#pragma unroll
    for (int i = 0; i < 4; ++i) {
      ushort4 a4, b4;
      a4.x = f2bfu(av[i].x); a4.y = f2bfu(av[i].y); a4.z = f2bfu(av[i].z); a4.w = f2bfu(av[i].w);
      b4.x = f2bfu(bv[i].x); b4.y = f2bfu(bv[i].y); b4.z = f2bfu(bv[i].z); b4.w = f2bfu(bv[i].w);
      *(ushort4*)&As[sr][sq * 16 + i * 4] = a4;
      *(ushort4*)&Bs[sr][sq * 16 + i * 4] = b4;
    }
    __syncthreads();
#pragma unroll
    for (int kk = 0; kk < 2; ++kk) {
      const int ko = kk * 32 + ((lane >> 4) << 3);
      short8 bf0 = *(const short8*)&Bs[wc * 32 + (lane & 15)][ko];
      short8 bf1 = *(const short8*)&Bs[wc * 32 + 16 + (lane & 15)][ko];
      short8 af0 = *(const short8*)&As[wr * 32 + (lane & 15)][ko];
      short8 af1 = *(const short8*)&As[wr * 32 + 16 + (lane & 15)][ko];
      acc[0][0] = __builtin_amdgcn_mfma_f32_16x16x32_bf16(af0, bf0, acc[0][0], 0, 0, 0);
      acc[0][1] = __builtin_amdgcn_mfma_f32_16x16x32_bf16(af0, bf1, acc[0][1], 0, 0, 0);
      acc[1][0] = __builtin_amdgcn_mfma_f32_16x16x32_bf16(af1, bf0, acc[1][0], 0, 0, 0);
      acc[1][1] = __builtin_amdgcn_mfma_f32_16x16x32_bf16(af1, bf1, acc[1][1], 0, 0, 0);
    }
  }

#pragma unroll
  for (int mt = 0; mt < 2; ++mt)
#pragma unroll
    for (int nt = 0; nt < 2; ++nt)
#pragma unroll
      for (int j = 0; j < 4; ++j) {
        const int m = g0 + wr * 32 + mt * 16 + ((lane >> 4) << 2) + j;
        const int n = n0 + wc * 32 + nt * 16 + (lane & 15);
        const int tl = n >> 5, b = n & 31;
        const float v = acc[mt][nt][j] + bias[m];
        xw[(((size_t)dir * Tseg + tl) * G4_N + m) * B_N + b] = f2bfu(v);
      }
}

// ---------------------------------------------------------------------------
// Kernel 2: persistent recurrence, single-hop TAGGED messages on the clean
// 512-thread skeleton. 64 wgs; dir = wg&1, cg = wg>>1.
//   msgs: [dir][parity][cg=32][b=32][c2=8] x 8B, msg = {hi32: tag, lo32: 2bf16}
//   tag t = "h state entering step t". Publish = ONE dwordx2 fire-and-forget.
// Consumer thread polls exactly the 16 contiguous messages (128B) it stages:
// producer cgp = tid>>4, rows b0=(tid&15)*2, b0+1, all 8 c2.
// Exact-tag safety: any wg publishing tag t+2 has passed poll t+1, which
// required every wg's tag-(t+1) publish, which is after ALL that wg's threads
// passed poll t (S1/S2 barriers) => slot for t is never overwritten under a
// live poll. 8B-aligned single-store messages cannot tear tag vs payload.
// ---------------------------------------------------------------------------
__global__ __launch_bounds__(512, 1) void rec_kernel(
    const unsigned short* __restrict__ xw,
    const float* __restrict__ w_hh_f, const float* __restrict__ w_hh_b,
    const float* __restrict__ w_cls, const int* __restrict__ lengths,
    ull* __restrict__ msgs,                  // [2][2][32][32][8] x 8B
    float* __restrict__ c_buf,               // [2][B][H]
    float* __restrict__ lpart,               // [64 wg][B][T][2]
    int t0, int Tseg)
{
  __shared__ unsigned short Ah[32][520];   // 33.3 KB, row stride 1040B
  __shared__ float gate_p[8][32][17];      // K-half partials
  __shared__ float lp[16][33][2];          // logits partials

  const int tid = threadIdx.x;
  const int wg = blockIdx.x;
  const int dir = wg & 1;
  const int cg = wg >> 1;
  const int colbase = cg * 16;
  const float* __restrict__ w_hh = dir ? w_hh_b : w_hh_f;
  const int w = tid >> 6, lane = tid & 63;
  const int q = w >> 1, kh = w & 1;

  // one-time: W_hh fragments (gate q, K-half kh) into registers
  short8 wfrag[8];
  {
    const int grow = q * 512 + colbase + (lane & 15);
    const int kb = (lane >> 4) << 3;
    const float* __restrict__ wr_ = &w_hh[(size_t)grow * H_N + kh * 256];
#pragma unroll
    for (int ks = 0; ks < 8; ++ks) {
      const float4 f0 = *(const float4*)&wr_[ks * 32 + kb];
      const float4 f1 = *(const float4*)&wr_[ks * 32 + kb + 4];
      short8 v;
      v[0] = (short)f2bfu(f0.x); v[1] = (short)f2bfu(f0.y);
      v[2] = (short)f2bfu(f0.z); v[3] = (short)f2bfu(f0.w);
      v[4] = (short)f2bfu(f1.x); v[5] = (short)f2bfu(f1.y);
      v[6] = (short)f2bfu(f1.z); v[7] = (short)f2bfu(f1.w);
      wfrag[ks] = v;
    }
  }

  // per-thread epilogue ownership: b = tid>>4 (32), cl = tid&15 (16 cols)
  const int b = tid >> 4;
  const int cl = tid & 15;
  const int col = colbase + cl;
  const int Lb = lengths[b];
  const int Lb_r = lengths[tid & 31];      // for the tid<64 logits reducer
  float cc = c_buf[((size_t)dir * B_N + b) * H_N + col];
  const float wc0 = w_cls[dir * H_N + col];
  const float wc1 = w_cls[2 * H_N + dir * H_N + col];

  // initial h (own column) from own message slot (coherent read)
  float hh;
  {
    const ull own = __hip_atomic_load(
        &msgs[((size_t)dir * 2 + (t0 & 1)) * 8192 + ((size_t)cg * 32 + b) * 8 + (cl >> 1)],
        __ATOMIC_RELAXED, __HIP_MEMORY_SCOPE_AGENT);
    hh = bfu2f((unsigned short)((own >> ((cl & 1) * 16)) & 0xffffu));
  }

  float* __restrict__ lslice = lpart + (size_t)wg * B_N * T_N * 2;

  // poll-set base: producer cgp = tid>>4, rows b0,b0+1 (16 msgs, 128B contig)
  const int b0 = (tid & 15) * 2;
  const int cg16 = (tid >> 4) * 16;
  const size_t pollbase = ((size_t)(tid >> 4) * 32 + b0) * 8;

  // prefetch step-0 xw gate values (plain cached loads)
  unsigned short xv[4];
  {
    const unsigned short* __restrict__ xb =
        &xw[((size_t)(dir * Tseg) * G4_N + colbase + cl) * B_N + b];
#pragma unroll
    for (int q2 = 0; q2 < 4; ++q2) xv[q2] = xb[(size_t)q2 * 512 * B_N];
  }

  for (int ts = 0; ts < Tseg; ++ts) {
    const int t = t0 + ts;

    // poll own 16 tagged messages until all carry tag t (data arrives WITH tag)
    ull m[16];
    {
      const ull* __restrict__ mb = msgs + ((size_t)dir * 2 + (t & 1)) * 8192 + pollbase;
      const unsigned int want = (unsigned int)t;
      bool ok;
      do {
#pragma unroll
        for (int j = 0; j < 16; ++j)
          m[j] = __hip_atomic_load(&mb[j], __ATOMIC_RELAXED, __HIP_MEMORY_SCOPE_AGENT);
        ok = true;
#pragma unroll
        for (int j = 0; j < 16; ++j)
          ok &= ((unsigned int)(m[j] >> 32) == want);
      } while (!ok);
    }
    // payloads (already in registers) -> Ah
#pragma unroll
    for (int j = 0; j < 16; ++j)
      *(unsigned int*)&Ah[b0 + (j >> 3)][cg16 + (j & 7) * 2] = (unsigned int)m[j];
    __syncthreads();  // S1: Ah complete

    // previous step's logits reduce (off critical path; barrier-ordered)
    if (ts > 0 && tid < 64) {
      const int br = tid & 31, tau = tid >> 5;
      const int tp = t - 1;
      if (tp < Lb_r) {
        float s = 0.f;
#pragma unroll
        for (int k = 0; k < 16; ++k) s += lp[k][br][tau];
        const int tpos = dir ? (Lb_r - 1 - tp) : tp;
        lslice[((size_t)br * T_N + tpos) * 2 + tau] = s;
      }
    }

    // MFMA: wave w computes gate q, K-half kh partials
    {
      f32x4 acc0 = {0.f, 0.f, 0.f, 0.f}, acc1 = {0.f, 0.f, 0.f, 0.f};
      const int kb = (lane >> 4) << 3;
#pragma unroll
      for (int ks = 0; ks < 8; ++ks) {
        const int kk = kh * 256 + (ks << 5) + kb;
        short8 a0 = *(const short8*)&Ah[(lane & 15)][kk];
        short8 a1 = *(const short8*)&Ah[16 + (lane & 15)][kk];
        acc0 = __builtin_amdgcn_mfma_f32_16x16x32_bf16(a0, wfrag[ks], acc0, 0, 0, 0);
        acc1 = __builtin_amdgcn_mfma_f32_16x16x32_bf16(a1, wfrag[ks], acc1, 0, 0, 0);
      }
      const int crow = (lane >> 4) << 2;
      const int ccol = lane & 15;
#pragma unroll
      for (int j = 0; j < 4; ++j) {
        gate_p[w][crow + j][ccol] = acc0[j];
        gate_p[w][16 + crow + j][ccol] = acc1[j];
      }
    }
    __syncthreads();  // S2: gate_p ready

    // epilogue: merge K-halves, gates + state update (fp32)
    const bool valid = (t < Lb);
    float hn;
    {
      const float gi = gate_p[0][b][cl] + gate_p[1][b][cl] + bfu2f(xv[0]);
      const float gf = gate_p[2][b][cl] + gate_p[3][b][cl] + bfu2f(xv[1]);
      const float gg = gate_p[4][b][cl] + gate_p[5][b][cl] + bfu2f(xv[2]);
      const float go = gate_p[6][b][cl] + gate_p[7][b][cl] + bfu2f(xv[3]);
      const float cn = sigmf(gf) * cc + sigmf(gi) * tanhf(gg);
      hn = sigmf(go) * tanhf(cn);
      if (valid) { cc = cn; hh = hn; }
    }

    // publish tagged message (fire-and-forget; adjacent cols packed via shfl)
    {
      const float hhp = __shfl_xor(hh, 1);
      if ((cl & 1) == 0) {
        const ull msg =
            ((ull)(unsigned int)(t + 1) << 32) |
            (ull)((unsigned int)f2bfu(hh) | ((unsigned int)f2bfu(hhp) << 16));
        store_msg(&msgs[((size_t)dir * 2 + ((t + 1) & 1)) * 8192 +
                        ((size_t)cg * 32 + b) * 8 + (cl >> 1)],
                  msg);
      }
    }
    lp[cl][b][0] = valid ? hn * wc0 : 0.f;
    lp[cl][b][1] = valid ? hn * wc1 : 0.f;

    // prefetch next step's xw (completes under next poll)
    if (ts + 1 < Tseg) {
      const unsigned short* __restrict__ xb =
          &xw[((size_t)(dir * Tseg + ts + 1) * G4_N + colbase + cl) * B_N + b];
#pragma unroll
      for (int q2 = 0; q2 < 4; ++q2) xv[q2] = xb[(size_t)q2 * 512 * B_N];
    }
    // no extra barrier: next S1 provides wg-wide ordering
  }

  // final step's logits reduce
  if (tid < 64) {
    const int br = tid & 31, tau = tid >> 5;
    const int tp = t0 + Tseg - 1;
    if (tp < Lb_r) {
      float s = 0.f;
#pragma unroll
      for (int k = 0; k < 16; ++k) s += lp[k][br][tau];
      const int tpos = dir ? (Lb_r - 1 - tp) : tp;
      lslice[((size_t)br * T_N + tpos) * 2 + tau] = s;
    }
  }

  // persist c across segment launches (h persists via msgs)
  c_buf[((size_t)dir * B_N + b) * H_N + col] = cc;
}

// ---------------------------------------------------------------------------
__global__ void init_kernel(ull* __restrict__ msgs, float* __restrict__ c_buf)
{
  const int i = blockIdx.x * 256 + threadIdx.x;  // 0..65535
  if (i < 2 * 2 * 32 * 32 * 8) msgs[i] = 0ull;   // tag 0, h = 0
  if (i < 2 * B_N * H_N) c_buf[i] = 0.f;
}

__global__ void reduce_softmax_kernel(const float* __restrict__ lpart,
                                      const float* __restrict__ b_cls,
                                      float* __restrict__ out)
{
  const int i = blockIdx.x * 256 + threadIdx.x;  // 0..32767
  if (i >= B_N * T_N) return;
  float s0 = b_cls[0], s1 = b_cls[1];
  const float* __restrict__ p = lpart + (size_t)i * 2;
#pragma unroll 8
  for (int wg = 0; wg < 64; ++wg) {
    s0 += p[(size_t)wg * B_N * T_N * 2];
    s1 += p[(size_t)wg * B_N * T_N * 2 + 1];
  }
  const float m = fmaxf(s0, s1);
  const float e0 = expf(s0 - m), e1 = expf(s1 - m);
  const float inv = 1.f / (e0 + e1);
  out[2 * i] = e0 * inv;
  out[2 * i + 1] = e1 * inv;
}

// ---------------------------------------------------------------------------
extern "C" void kernel_launch(void* const* d_in, const int* in_sizes, int n_in,
                              void* d_out, int out_size, void* d_ws, size_t ws_size,
                              hipStream_t stream)
{
  const float* xs      = (const float*)d_in[0];
  const int*   lengths = (const int*)d_in[1];
  const float* w_ih_f  = (const float*)d_in[3];
  const float* w_hh_f  = (const float*)d_in[4];
  const float* b_f     = (const float*)d_in[5];
  const float* w_ih_b  = (const float*)d_in[6];
  const float* w_hh_b  = (const float*)d_in[7];
  const float* b_b     = (const float*)d_in[8];
  const float* w_cls   = (const float*)d_in[9];
  const float* b_cls   = (const float*)d_in[10];
  float* out = (float*)d_out;

  auto alignup = [](size_t v) { return (v + 255) & ~(size_t)255; };
  const size_t msgs_b  = alignup((size_t)2 * 2 * 32 * 32 * 8 * 8);    // 128 KB
  const size_t cbuf_b  = alignup((size_t)2 * B_N * H_N * 4);          // 128 KB
  const size_t lpart_b = alignup((size_t)64 * B_N * T_N * 2 * 4);     // 16 MB
  const size_t fixed = msgs_b + cbuf_b + lpart_b + 1024;

  int nseg = 1;
  while (nseg < 64) {
    const size_t xwb = alignup((size_t)2 * (T_N / nseg) * G4_N * B_N * 2);
    if (xwb + fixed <= ws_size) break;
    nseg <<= 1;
  }
  const int Tseg = T_N / nseg;
  const size_t xw_b = alignup((size_t)2 * Tseg * G4_N * B_N * 2);

  char* p = (char*)d_ws;
  unsigned short* xw = (unsigned short*)p;  p += xw_b;
  ull* msgs = (ull*)p;                      p += msgs_b;
  float* c_buf = (float*)p;                 p += cbuf_b;
  float* lpart = (float*)p;                 p += lpart_b;

  hipMemsetAsync(lpart, 0, lpart_b, stream);
  init_kernel<<<256, 256, 0, stream>>>(msgs, c_buf);

  for (int s = 0; s < nseg; ++s) {
    const int t0 = s * Tseg;
    dim3 g(G4_N / 64, (Tseg * B_N) / 64, 2);
    xw_gemm_kernel<<<g, 256, 0, stream>>>(xs, lengths, w_ih_f, b_f, w_ih_b, b_b, xw, t0, Tseg);
    rec_kernel<<<64, 512, 0, stream>>>(xw, w_hh_f, w_hh_b, w_cls, lengths,
                                       msgs, c_buf, lpart, t0, Tseg);
  }

  reduce_softmax_kernel<<<128, 256, 0, stream>>>(lpart, b_cls, out);
}

// Round 10
// 4690.614 us; speedup vs baseline: 1.5313x; 1.5313x over previous
//
#include <hip/hip_runtime.h>
#include <math.h>

#define B_N 32
#define T_N 1024
#define E_N 512
#define H_N 512
#define G4_N 2048  // 4*H
#define NREC 64
#define NGEMM 192

typedef __attribute__((ext_vector_type(8))) short short8;
typedef __attribute__((ext_vector_type(4))) float f32x4;
typedef __attribute__((ext_vector_type(4))) unsigned int uint32x4;
typedef unsigned long long ull;

__device__ __forceinline__ unsigned short f2bfu(float f) {
  unsigned int x = __builtin_bit_cast(unsigned int, f);
  x += 0x7fffu + ((x >> 16) & 1u);
  return (unsigned short)(x >> 16);
}
__device__ __forceinline__ float bfu2f(unsigned short u) {
  return __builtin_bit_cast(float, ((unsigned int)u) << 16);
}
__device__ __forceinline__ float sigmf(float x) { return 1.0f / (1.0f + expf(-x)); }

// ---- agent-scope (MALL-coherent, bypass L1/L2) access helpers -------------
// h slice (64B) + this thread's 4 xw gate values (8B) in one drained batch:
// the xw load's latency is fully absorbed by the vmcnt(0) already needed for h.
__device__ __forceinline__ void load_h_xw(const unsigned short* ph, const unsigned short* px,
                                          uint32x4& a, uint32x4& b,
                                          uint32x4& c, uint32x4& d, ull& x) {
  asm volatile("global_load_dwordx4 %0, %5, off sc0 sc1\n\t"
               "global_load_dwordx4 %1, %5, off offset:16 sc0 sc1\n\t"
               "global_load_dwordx4 %2, %5, off offset:32 sc0 sc1\n\t"
               "global_load_dwordx4 %3, %5, off offset:48 sc0 sc1\n\t"
               "global_load_dwordx2 %4, %6, off sc0 sc1\n\t"
               "s_waitcnt vmcnt(0)"
               : "=&v"(a), "=&v"(b), "=&v"(c), "=&v"(d), "=&v"(x)
               : "v"(ph), "v"(px) : "memory");
}
__device__ __forceinline__ void store32_mall(unsigned int* p, unsigned int v) {
  asm volatile("global_store_dword %0, %1, off sc0 sc1" :: "v"(p), "v"(v) : "memory");
}
__device__ __forceinline__ void store16_mall(unsigned short* p, unsigned short v) {
  unsigned int vv = v;
  asm volatile("global_store_short %0, %1, off sc0 sc1" :: "v"(p), "v"(vv) : "memory");
}

// Pipelined 2-deep flag poll (R8). On exit up to ONE flag load is still
// outstanding — drained by load_h_xw's internal vmcnt(0) before data use.
__device__ __forceinline__ void poll_flag2(const unsigned int* pf, unsigned int want) {
  unsigned int fa, fb;
  asm volatile("global_load_dword %0, %2, off sc0 sc1\n\t"
               "global_load_dword %1, %2, off sc0 sc1"
               : "=&v"(fa), "=&v"(fb) : "v"(pf) : "memory");
  for (;;) {
    asm volatile("s_waitcnt vmcnt(1)" ::: "memory");
    __builtin_amdgcn_sched_barrier(0);
    if (fa >= want) break;
    asm volatile("global_load_dword %0, %1, off sc0 sc1" : "=&v"(fa) : "v"(pf) : "memory");
    asm volatile("s_waitcnt vmcnt(1)" ::: "memory");
    __builtin_amdgcn_sched_barrier(0);
    if (fb >= want) break;
    asm volatile("global_load_dword %0, %1, off sc0 sc1" : "=&v"(fb) : "v"(pf) : "memory");
  }
}

// ---------------------------------------------------------------------------
// Fused kernel: blocks 0..63 = persistent recurrence (R8 transport);
// blocks 64..255 = xw GEMM producing xwp[dir][tl][col(512)][b(32)][gate(4)]
// bf16 via sc0 sc1 stores, time-major tile order, with per-(dir,t-chunk)
// completion counters (value 32 = all gate tiles of that 2-step chunk at MALL).
// One-way dependency rec<-gemm; all 256 blocks co-resident (512 thr, 55KB LDS,
// <=16 waves/CU worst-case pairing) => deadlock-free.
// Early stop: steps t >= Lmax (= lengths[0], sorted desc) are no-ops; all
// blocks read the same Lmax => uniform trip counts, protocol intact.
// ---------------------------------------------------------------------------
__global__ __launch_bounds__(512, 1) void fused_kernel(
    const float* __restrict__ xs, const int* __restrict__ lengths,
    const float* __restrict__ w_ih_f, const float* __restrict__ b_f,
    const float* __restrict__ w_ih_b, const float* __restrict__ b_b,
    const float* __restrict__ w_hh_f, const float* __restrict__ w_hh_b,
    const float* __restrict__ w_cls,
    unsigned short* __restrict__ xwp,        // [2][Tseg][512][32][4] bf16
    unsigned short* __restrict__ hx,         // [2][2][32][32][16] bf16
    unsigned int* __restrict__ flg,          // [2][32][8] u32
    unsigned int* __restrict__ cnt,          // [2][512] u32 (global t/2 index)
    float* __restrict__ c_buf,               // [2][B][H]
    float* __restrict__ lpart,               // [64 wg][B][T][2]
    int t0, int Tseg)
{
  __shared__ alignas(16) unsigned char smem[55296];
  const int tid = threadIdx.x;
  const int Lmax = lengths[0];
  const int w = tid >> 6, lane = tid & 63;

  if (blockIdx.x >= NREC) {
    // ===================== GEMM role =====================
    unsigned short* As = (unsigned short*)smem;            // [64][80]
    unsigned short* Bs = (unsigned short*)(smem + 10240);  // [64][80]
    const int g = blockIdx.x - NREC;
    const int wr = w >> 2, wc = w & 3;          // 8 waves: 2(m) x 4(n)
    const int sr = tid >> 3, sq = tid & 7;      // staging: 8 thr/row, 8 floats
    const int ntau = (Tseg >> 1) << 6;          // chunks * 64 tiles (2 dirs x 32)

    for (int tau = g; tau < ntau; tau += NGEMM) {
      const int gtile = tau & 31;
      const int dir = (tau >> 5) & 1;
      const int tchunk = tau >> 6;
      const int tt0g = t0 + tchunk * 2;
      if (tt0g < Lmax) {
        const int g0 = gtile * 64;
        const float* __restrict__ W = dir ? w_ih_b : w_ih_f;
        const float* __restrict__ bias = dir ? b_b : b_f;
        const int bb = sr & 31;
        const int tt = tt0g + (sr >> 5);
        const int Lb = lengths[bb];
        const int src_t = (dir != 0 && tt < Lb) ? (Lb - 1 - tt) : tt;
        const float* __restrict__ xrow = xs + ((size_t)bb * T_N + src_t) * E_N;
        const float* __restrict__ arow = W + (size_t)(g0 + sr) * E_N;
        f32x4 accm[2] = {};

        for (int k0 = 0; k0 < E_N; k0 += 64) {
          const float4 av0 = *(const float4*)&arow[k0 + sq * 8];
          const float4 av1 = *(const float4*)&arow[k0 + sq * 8 + 4];
          const float4 bv0 = *(const float4*)&xrow[k0 + sq * 8];
          const float4 bv1 = *(const float4*)&xrow[k0 + sq * 8 + 4];
          __syncthreads();  // protect previous iteration's fragment reads
          ushort4 u;
          u.x = f2bfu(av0.x); u.y = f2bfu(av0.y); u.z = f2bfu(av0.z); u.w = f2bfu(av0.w);
          *(ushort4*)&As[sr * 80 + sq * 8] = u;
          u.x = f2bfu(av1.x); u.y = f2bfu(av1.y); u.z = f2bfu(av1.z); u.w = f2bfu(av1.w);
          *(ushort4*)&As[sr * 80 + sq * 8 + 4] = u;
          u.x = f2bfu(bv0.x); u.y = f2bfu(bv0.y); u.z = f2bfu(bv0.z); u.w = f2bfu(bv0.w);
          *(ushort4*)&Bs[sr * 80 + sq * 8] = u;
          u.x = f2bfu(bv1.x); u.y = f2bfu(bv1.y); u.z = f2bfu(bv1.z); u.w = f2bfu(bv1.w);
          *(ushort4*)&Bs[sr * 80 + sq * 8 + 4] = u;
          __syncthreads();
#pragma unroll
          for (int kk = 0; kk < 2; ++kk) {
            const int ko = kk * 32 + ((lane >> 4) << 3);
            short8 bf  = *(const short8*)&Bs[(wc * 16 + (lane & 15)) * 80 + ko];
            short8 af0 = *(const short8*)&As[(wr * 32 + (lane & 15)) * 80 + ko];
            short8 af1 = *(const short8*)&As[(wr * 32 + 16 + (lane & 15)) * 80 + ko];
            accm[0] = __builtin_amdgcn_mfma_f32_16x16x32_bf16(af0, bf, accm[0], 0, 0, 0);
            accm[1] = __builtin_amdgcn_mfma_f32_16x16x32_bf16(af1, bf, accm[1], 0, 0, 0);
          }
        }
        // epilogue: sc0 sc1 stores into [tl][col][b][q] layout
#pragma unroll
        for (int mt = 0; mt < 2; ++mt)
#pragma unroll
          for (int j = 0; j < 4; ++j) {
            const int m = g0 + wr * 32 + mt * 16 + ((lane >> 4) << 2) + j;
            const int n = tchunk * 64 + wc * 16 + (lane & 15);
            const int tl = n >> 5, b = n & 31;
            const int qg = m >> 9, colg = m & 511;
            const float v = accm[mt][j] + bias[m];
            store16_mall(&xwp[((((size_t)dir * Tseg + tl) * 512 + colg) * 32 + b) * 4 + qg],
                         f2bfu(v));
          }
        asm volatile("s_waitcnt vmcnt(0)" ::: "memory");  // per-wave drain
      }
      __syncthreads();  // all waves drained (uniform branch across block)
      if (tid == 0 && tt0g < Lmax)
        __hip_atomic_fetch_add(&cnt[dir * 512 + ((unsigned)tt0g >> 1)], 1u,
                               __ATOMIC_RELAXED, __HIP_MEMORY_SCOPE_AGENT);
    }
    return;
  }

  // ===================== REC role (R8 transport) =====================
  unsigned short (*Ah)[520] = (unsigned short (*)[520])smem;          // 33280B
  float (*gate_p)[32][17] = (float (*)[32][17])(smem + 33280);        // 17408B
  float (*lp)[33][2] = (float (*)[33][2])(smem + 50688);              // 4224B

  const int wg = blockIdx.x;
  const int dir = wg & 1;
  const int cg = wg >> 1;
  const int colbase = cg * 16;
  const float* __restrict__ w_hh = dir ? w_hh_b : w_hh_f;
  const int q = w >> 1, kh = w & 1;

  // one-time: W_hh fragments (gate q, K-half kh) into registers
  short8 wfrag[8];
  {
    const int grow = q * 512 + colbase + (lane & 15);
    const int kb = (lane >> 4) << 3;
    const float* __restrict__ wr_ = &w_hh[(size_t)grow * H_N + kh * 256];
#pragma unroll
    for (int ks = 0; ks < 8; ++ks) {
      const float4 f0 = *(const float4*)&wr_[ks * 32 + kb];
      const float4 f1 = *(const float4*)&wr_[ks * 32 + kb + 4];
      short8 v;
      v[0] = (short)f2bfu(f0.x); v[1] = (short)f2bfu(f0.y);
      v[2] = (short)f2bfu(f0.z); v[3] = (short)f2bfu(f0.w);
      v[4] = (short)f2bfu(f1.x); v[5] = (short)f2bfu(f1.y);
      v[6] = (short)f2bfu(f1.z); v[7] = (short)f2bfu(f1.w);
      wfrag[ks] = v;
    }
  }

  const int b = tid >> 4;
  const int cl = tid & 15;
  const int col = colbase + cl;
  const int Lb = lengths[b];
  const int Lb_r = lengths[tid & 31];
  float cc = c_buf[((size_t)dir * B_N + b) * H_N + col];
  const float wc0 = w_cls[dir * H_N + col];
  const float wc1 = w_cls[2 * H_N + dir * H_N + col];
  float hh = bfu2f(hx[((size_t)dir * 2 + (t0 & 1)) * 16384 + ((size_t)cg * 32 + b) * 16 + cl]);

  float* __restrict__ lslice = lpart + (size_t)wg * B_N * T_N * 2;
  unsigned int* __restrict__ myflag = flg + ((size_t)dir * 32 + cg) * 8 + w;
  const unsigned int* __restrict__ pollflag =
      flg + ((size_t)dir * 32 + (tid >> 4)) * 8 + ((tid & 15) >> 1);

  const int b0 = (tid & 15) * 2, cg16 = (tid >> 4) * 16;
  const int Tloc = min(Tseg, max(0, Lmax - t0));

  for (int ts = 0; ts < Tloc; ++ts) {
    const int t = t0 + ts;

    // xw chunk readiness (chunk = 2 steps; check on even t / first step).
    // GEMM runs far ahead of the 3.8us/step cadence => never spins in steady
    // state; only a short startup wait on the very first chunks.
    if ((t & 1) == 0 || ts == 0) {
      const unsigned int* cp = cnt + dir * 512 + ((unsigned)t >> 1);
      while (__hip_atomic_load(cp, __ATOMIC_RELAXED, __HIP_MEMORY_SCOPE_AGENT) < 32u) {}
    }

    // wait for the producer WAVE covering this thread's slice
    poll_flag2(pollflag, (unsigned int)t);

    // bulk-load h slice + this thread's 4 xw gate values (one drained batch)
    ull xvp;
    {
      uint32x4 va, vb, vc, vd;
      load_h_xw(hx + ((size_t)dir * 2 + (t & 1)) * 16384 + (size_t)tid * 32,
                xwp + ((((size_t)dir * Tseg + ts) * 512 + col) * 32 + b) * 4,
                va, vb, vc, vd, xvp);
      *(uint32x4*)&Ah[b0][cg16] = va;
      *(uint32x4*)&Ah[b0][cg16 + 8] = vb;
      *(uint32x4*)&Ah[b0 + 1][cg16] = vc;
      *(uint32x4*)&Ah[b0 + 1][cg16 + 8] = vd;
    }
    __syncthreads();  // S1: Ah complete

    // previous step's logits reduce (off critical path; barrier-ordered)
    if (ts > 0 && tid < 64) {
      const int br = tid & 31, tau = tid >> 5;
      const int tp = t - 1;
      if (tp < Lb_r) {
        float s = 0.f;
#pragma unroll
        for (int k = 0; k < 16; ++k) s += lp[k][br][tau];
        const int tpos = dir ? (Lb_r - 1 - tp) : tp;
        lslice[((size_t)br * T_N + tpos) * 2 + tau] = s;
      }
    }

    // MFMA: wave w computes gate q, K-half kh partials
    {
      f32x4 acc0 = {0.f, 0.f, 0.f, 0.f}, acc1 = {0.f, 0.f, 0.f, 0.f};
      const int kb = (lane >> 4) << 3;
#pragma unroll
      for (int ks = 0; ks < 8; ++ks) {
        const int kk = kh * 256 + (ks << 5) + kb;
        short8 a0 = *(const short8*)&Ah[(lane & 15)][kk];
        short8 a1 = *(const short8*)&Ah[16 + (lane & 15)][kk];
        acc0 = __builtin_amdgcn_mfma_f32_16x16x32_bf16(a0, wfrag[ks], acc0, 0, 0, 0);
        acc1 = __builtin_amdgcn_mfma_f32_16x16x32_bf16(a1, wfrag[ks], acc1, 0, 0, 0);
      }
      const int crow = (lane >> 4) << 2;
      const int ccol = lane & 15;
#pragma unroll
      for (int j = 0; j < 4; ++j) {
        gate_p[w][crow + j][ccol] = acc0[j];
        gate_p[w][16 + crow + j][ccol] = acc1[j];
      }
    }
    __syncthreads();  // S2: gate_p ready

    // epilogue: merge K-halves, gates + state update (fp32)
    const bool valid = (t < Lb);
    float hn;
    {
      const float gi = gate_p[0][b][cl] + gate_p[1][b][cl] + bfu2f((unsigned short)(xvp & 0xffffu));
      const float gf = gate_p[2][b][cl] + gate_p[3][b][cl] + bfu2f((unsigned short)((xvp >> 16) & 0xffffu));
      const float gg = gate_p[4][b][cl] + gate_p[5][b][cl] + bfu2f((unsigned short)((xvp >> 32) & 0xffffu));
      const float go = gate_p[6][b][cl] + gate_p[7][b][cl] + bfu2f((unsigned short)((xvp >> 48) & 0xffffu));
      const float cn = sigmf(gf) * cc + sigmf(gi) * tanhf(gg);
      hn = sigmf(go) * tanhf(cn);
      if (valid) { cc = cn; hh = hn; }
    }

    // publish h pair (MALL write-through); adjacent cols packed via shfl
    {
      const float hhp = __shfl_xor(hh, 1);
      if ((cl & 1) == 0) {
        const unsigned int pv =
            (unsigned int)f2bfu(hh) | ((unsigned int)f2bfu(hhp) << 16);
        store32_mall((unsigned int*)(hx + ((size_t)dir * 2 + ((t + 1) & 1)) * 16384 +
                                     ((size_t)cg * 32 + b) * 16 + cl),
                     pv);
      }
    }
    lp[cl][b][0] = valid ? hn * wc0 : 0.f;
    lp[cl][b][1] = valid ? hn * wc1 : 0.f;

    // per-WAVE drain + flag (no third barrier)
    asm volatile("s_waitcnt vmcnt(0)" ::: "memory");
    __builtin_amdgcn_sched_barrier(0);
    if (lane == 0)
      store32_mall(myflag, (unsigned int)(t + 1));
  }

  // final computed step's logits reduce
  if (Tloc > 0 && tid < 64) {
    const int br = tid & 31, tau = tid >> 5;
    const int tp = t0 + Tloc - 1;
    if (tp < Lb_r) {
      float s = 0.f;
#pragma unroll
      for (int k = 0; k < 16; ++k) s += lp[k][br][tau];
      const int tpos = dir ? (Lb_r - 1 - tp) : tp;
      lslice[((size_t)br * T_N + tpos) * 2 + tau] = s;
    }
  }

  // persist c across segment launches (h persists via hx)
  c_buf[((size_t)dir * B_N + b) * H_N + col] = cc;
}

// ---------------------------------------------------------------------------
__global__ void init_kernel(ull* __restrict__ hx64, float* __restrict__ c_buf,
                            unsigned int* __restrict__ flg,
                            unsigned int* __restrict__ cnt)
{
  const int i = blockIdx.x * 256 + threadIdx.x;  // 0..65535
  if (i < 16384) hx64[i] = 0ull;                 // hx: 128 KB of zeros
  if (i < 2 * B_N * H_N) c_buf[i] = 0.f;
  if (i < 1024) flg[i] = 0u;
  if (i < 1024) cnt[i] = 0u;
}

__global__ void reduce_softmax_kernel(const float* __restrict__ lpart,
                                      const float* __restrict__ b_cls,
                                      float* __restrict__ out)
{
  const int i = blockIdx.x * 256 + threadIdx.x;  // 0..32767
  if (i >= B_N * T_N) return;
  float s0 = b_cls[0], s1 = b_cls[1];
  const float* __restrict__ p = lpart + (size_t)i * 2;
#pragma unroll 8
  for (int wg = 0; wg < 64; ++wg) {
    s0 += p[(size_t)wg * B_N * T_N * 2];
    s1 += p[(size_t)wg * B_N * T_N * 2 + 1];
  }
  const float m = fmaxf(s0, s1);
  const float e0 = expf(s0 - m), e1 = expf(s1 - m);
  const float inv = 1.f / (e0 + e1);
  out[2 * i] = e0 * inv;
  out[2 * i + 1] = e1 * inv;
}

// ---------------------------------------------------------------------------
extern "C" void kernel_launch(void* const* d_in, const int* in_sizes, int n_in,
                              void* d_out, int out_size, void* d_ws, size_t ws_size,
                              hipStream_t stream)
{
  const float* xs      = (const float*)d_in[0];
  const int*   lengths = (const int*)d_in[1];
  const float* w_ih_f  = (const float*)d_in[3];
  const float* w_hh_f  = (const float*)d_in[4];
  const float* b_f     = (const float*)d_in[5];
  const float* w_ih_b  = (const float*)d_in[6];
  const float* w_hh_b  = (const float*)d_in[7];
  const float* b_b     = (const float*)d_in[8];
  const float* w_cls   = (const float*)d_in[9];
  const float* b_cls   = (const float*)d_in[10];
  float* out = (float*)d_out;

  auto alignup = [](size_t v) { return (v + 255) & ~(size_t)255; };
  const size_t hx_b    = alignup((size_t)2 * 2 * 32 * 32 * 16 * 2);   // 128 KB
  const size_t flg_b   = alignup((size_t)1024 * 4);                   // 4 KB
  const size_t cnt_b   = alignup((size_t)1024 * 4);                   // 4 KB
  const size_t cbuf_b  = alignup((size_t)2 * B_N * H_N * 4);          // 128 KB
  const size_t lpart_b = alignup((size_t)64 * B_N * T_N * 2 * 4);     // 16 MB
  const size_t fixed = hx_b + flg_b + cnt_b + cbuf_b + lpart_b + 1024;

  int nseg = 1;
  while (nseg < 64) {
    const size_t xwb = alignup((size_t)2 * (T_N / nseg) * G4_N * B_N * 2);
    if (xwb + fixed <= ws_size) break;
    nseg <<= 1;
  }
  const int Tseg = T_N / nseg;
  const size_t xw_b = alignup((size_t)2 * Tseg * G4_N * B_N * 2);

  char* p = (char*)d_ws;
  unsigned short* xwp = (unsigned short*)p; p += xw_b;
  unsigned short* hx = (unsigned short*)p;  p += hx_b;
  unsigned int* flg = (unsigned int*)p;     p += flg_b;
  unsigned int* cnt = (unsigned int*)p;     p += cnt_b;
  float* c_buf = (float*)p;                 p += cbuf_b;
  float* lpart = (float*)p;                 p += lpart_b;

  hipMemsetAsync(lpart, 0, lpart_b, stream);
  init_kernel<<<256, 256, 0, stream>>>((ull*)hx, c_buf, flg, cnt);

  for (int s = 0; s < nseg; ++s) {
    const int t0 = s * Tseg;
    fused_kernel<<<NREC + NGEMM, 512, 0, stream>>>(
        xs, lengths, w_ih_f, b_f, w_ih_b, b_b, w_hh_f, w_hh_b, w_cls,
        xwp, hx, flg, cnt, c_buf, lpart, t0, Tseg);
  }

  reduce_softmax_kernel<<<128, 256, 0, stream>>>(lpart, b_cls, out);
}